// Round 6
// baseline (1559.394 us; speedup 1.0000x reference)
//
#include <hip/hip_runtime.h>

// LSTMPredictor: 2-layer LSTMCell (H=51), L=1000 steps + 100 autoregressive,
// B=256 chains. One block/batch element (grid=256=#CUs), 768 threads.
//
// R6: STOP fighting the register allocator (R1-R5: compiler refuses to keep
// 51 loop-invariant weights/thread in VGPRs; pinning them just moved the
// reload to scratch). Weights now live in LDS, TRANSPOSED (Wt[k][j]) so the
// per-step stream is bank-conflict-free: lane j reads (k*204+j)*4 -> lanes
// hit consecutive banks. Every weight read is ds_read_b32 with a constant
// offset (k*204*4 <= 40800 < 64K imm). h is broadcast via 13 uniform
// ds_read_b128 into intra-iteration temps. Deterministic LDS-BW floor:
// 122KB/step @ 256B/clk ~ 490 clk.
//
// Groups (same as R5): G0 (tid 0..203) -> W_hh1 row j (gates1 partial for
// h1(t+1)); G1 (tid 256..459) -> W_ih2; G2 (tid 512..715) -> W_hh2.
// Hot loop 2 barriers/step; future loop (x <- out_s feedback) 3 barriers.
// x streamed via uniform scalar load (saves LDS; total smem < 128 KiB).

#define B_   256
#define L_   1000
#define H_   51
#define HP   52
#define G4   204
#define T_   1100
#define KW   (H_ * G4)          // 10404 floats per transposed matrix
#define SM_FLOATS (3*KW + 3*G4 + 2*HP + 4)

__device__ __forceinline__ float frcp(float v) { return __builtin_amdgcn_rcpf(v); }
__device__ __forceinline__ float sigf(float v) {
    return frcp(1.0f + __expf(-v));
}
__device__ __forceinline__ float tanh_fast(float v) {
    float a = fminf(fmaxf(v, -9.0f), 9.0f);
    float e = __expf(2.0f * a);
    return (e - 1.0f) * frcp(e + 1.0f);
}

// one float4 h-chunk against 4 weights from the thread's LDS column
#define DOTQ(q, hv) do { \
    a0 = fmaf(wc[(4*(q)+0)*G4], (hv).x, a0); \
    a1 = fmaf(wc[(4*(q)+1)*G4], (hv).y, a1); \
    a2 = fmaf(wc[(4*(q)+2)*G4], (hv).z, a2); \
    a3 = fmaf(wc[(4*(q)+3)*G4], (hv).w, a3); } while (0)

#define MATVEC() do { \
    const float4* h4 = (const float4*)hsrc; \
    float4 v0 = h4[0], v1 = h4[1], v2 = h4[2], v3 = h4[3]; \
    float4 v4 = h4[4], v5 = h4[5], v6 = h4[6], v7 = h4[7]; \
    float4 v8 = h4[8], v9 = h4[9], v10 = h4[10], v11 = h4[11], v12 = h4[12]; \
    float a0 = bias, a1 = 0.f, a2 = 0.f, a3 = 0.f; \
    DOTQ(0, v0);  DOTQ(1, v1);  DOTQ(2, v2);  DOTQ(3, v3); \
    DOTQ(4, v4);  DOTQ(5, v5);  DOTQ(6, v6);  DOTQ(7, v7); \
    DOTQ(8, v8);  DOTQ(9, v9);  DOTQ(10, v10); DOTQ(11, v11); \
    a0 = fmaf(wc[48*G4], v12.x, a0); \
    a1 = fmaf(wc[49*G4], v12.y, a1); \
    a2 = fmaf(wc[50*G4], v12.z, a2); \
    gdst[0] = (a0 + a1) + (a2 + a3); } while (0)

__global__ __launch_bounds__(768, 3)
void lstm_pred_kernel(const float* __restrict__ x,
                      const float* __restrict__ W_ih1, const float* __restrict__ W_hh1,
                      const float* __restrict__ b_ih1, const float* __restrict__ b_hh1,
                      const float* __restrict__ W_ih2, const float* __restrict__ W_hh2,
                      const float* __restrict__ b_ih2, const float* __restrict__ b_hh2,
                      const float* __restrict__ W_lin, const float* __restrict__ b_lin,
                      float* __restrict__ out)
{
    extern __shared__ float smem[];
    float* Wlds  = smem;                 // [3][51][204] transposed weights
    float* gall  = smem + 3 * KW;        // [3*204]: g1partial | gatesA | gatesB
    float* hs0   = gall + 3 * G4;        // h1 [52]
    float* hs1   = hs0 + HP;             // h2 [52]
    float* out_p = hs1 + HP;             // out_s

    const int tid = threadIdx.x;
    const int b   = blockIdx.x;
    const int g   = tid >> 8;            // 0,1,2
    const int j   = tid & 255;
    const bool act = (j < G4);

    // ---- stage weights transposed into LDS (one-time, coalesced reads) ----
    {
        const float* srcs[3] = { W_hh1, W_ih2, W_hh2 };
#pragma unroll
        for (int m = 0; m < 3; ++m) {
            const float* S = srcs[m];
            float* D = Wlds + m * KW;
            for (int i = tid; i < KW; i += 768) {
                int r = i / H_;
                int k = i - r * H_;
                D[k * G4 + r] = S[i];
            }
        }
    }
    if (tid < HP) { hs0[tid] = 0.0f; hs1[tid] = 0.0f; }

    float bias = 0.0f;
    if (act) {
        if (g == 0)      bias = b_ih1[j] + b_hh1[j];
        else if (g == 1) bias = b_ih2[j] + b_hh2[j];
    }
    const float* wc   = Wlds + g * KW + j;          // thread's weight column
    const float* hsrc = (g == 2) ? hs1 : hs0;       // h-source
    float* gdst = gall + g * G4 + j;

    // update-lane extras
    float wi0 = 0.f, wi1 = 0.f, wi2 = 0.f, wi3 = 0.f, wlin = 0.f;
    if (tid < H_) {
        wi0 = W_ih1[tid];
        wi1 = W_ih1[tid + H_];
        wi2 = W_ih1[tid + 2 * H_];
        wi3 = W_ih1[tid + 3 * H_];
    }
    if (tid >= 256 && tid < 256 + H_) wlin = W_lin[tid - 256];
    const float blin = b_lin[0];
    const float* xg  = x + (size_t)b * L_;

    float c1 = 0.f, c2 = 0.f;
    float* outp = out + (size_t)b * T_;

    // ---- prologue: h1(0) (h1(-1)=0 -> gates1 partial = bias1) ----
    if (g == 0 && act) gall[j] = bias;
    __syncthreads();
    if (tid < H_) {
        const float xv = xg[0];
        float gi = fmaf(wi0, xv, gall[tid]);
        float gf = fmaf(wi1, xv, gall[tid + H_]);
        float gg = fmaf(wi2, xv, gall[tid + 2 * H_]);
        float go = fmaf(wi3, xv, gall[tid + 3 * H_]);
        float ig = sigf(gi), fg = sigf(gf), gv = tanh_fast(gg), og = sigf(go);
        c1 = fmaf(fg, c1, ig * gv);
        hs0[tid] = og * tanh_fast(c1);
    }
    __syncthreads();

    // ========== hot loop: t = 0..998, 2 barriers/step ==========
    for (int t = 0; t < L_ - 1; ++t) {
        // prefetch next x (uniform -> scalar load, latency hidden by matvec)
        const float xnext = xg[t + 1];
        if (act) MATVEC();
        __syncthreads();

        // Phase B1 (wave 4): h2(t) update + output out(t)
        if (tid >= 256 && tid < 320) {
            float p = 0.f;
            const int q2 = tid - 256;
            if (q2 < H_) {
                float gi = gall[G4 + q2]        + gall[2*G4 + q2];
                float gf = gall[G4 + q2 +   H_] + gall[2*G4 + q2 +   H_];
                float gg = gall[G4 + q2 + 2*H_] + gall[2*G4 + q2 + 2*H_];
                float go = gall[G4 + q2 + 3*H_] + gall[2*G4 + q2 + 3*H_];
                float ig = sigf(gi), fg = sigf(gf), gv = tanh_fast(gg), og = sigf(go);
                c2 = fmaf(fg, c2, ig * gv);
                float h2n = og * tanh_fast(c2);
                hs1[q2] = h2n;
                p = h2n * wlin;
            }
#pragma unroll
            for (int off = 32; off > 0; off >>= 1) p += __shfl_down(p, off);
            if (q2 == 0) outp[t] = p + blin;
        }
        // Phase B2 (wave 0, concurrent): h1(t+1)
        if (tid < H_) {
            float gi = fmaf(wi0, xnext, gall[tid]);
            float gf = fmaf(wi1, xnext, gall[tid + H_]);
            float gg = fmaf(wi2, xnext, gall[tid + 2 * H_]);
            float go = fmaf(wi3, xnext, gall[tid + 3 * H_]);
            float ig = sigf(gi), fg = sigf(gf), gv = tanh_fast(gg), og = sigf(go);
            c1 = fmaf(fg, c1, ig * gv);
            hs0[tid] = og * tanh_fast(c1);
        }
        __syncthreads();
    }

    // ========== future loop: t = 999..1099 (x <- out_s), 3 barriers ==========
    for (int t = L_ - 1; t < T_; ++t) {
        if (act) MATVEC();
        __syncthreads();

        if (tid >= 256 && tid < 320) {
            float p = 0.f;
            const int q2 = tid - 256;
            if (q2 < H_) {
                float gi = gall[G4 + q2]        + gall[2*G4 + q2];
                float gf = gall[G4 + q2 +   H_] + gall[2*G4 + q2 +   H_];
                float gg = gall[G4 + q2 + 2*H_] + gall[2*G4 + q2 + 2*H_];
                float go = gall[G4 + q2 + 3*H_] + gall[2*G4 + q2 + 3*H_];
                float ig = sigf(gi), fg = sigf(gf), gv = tanh_fast(gg), og = sigf(go);
                c2 = fmaf(fg, c2, ig * gv);
                float h2n = og * tanh_fast(c2);
                hs1[q2] = h2n;
                p = h2n * wlin;
            }
#pragma unroll
            for (int off = 32; off > 0; off >>= 1) p += __shfl_down(p, off);
            if (q2 == 0) { float o = p + blin; *out_p = o; outp[t] = o; }
        }
        __syncthreads();   // out_s visible to wave 0

        if (tid < H_) {
            const float xv = *out_p;
            float gi = fmaf(wi0, xv, gall[tid]);
            float gf = fmaf(wi1, xv, gall[tid + H_]);
            float gg = fmaf(wi2, xv, gall[tid + 2 * H_]);
            float go = fmaf(wi3, xv, gall[tid + 3 * H_]);
            float ig = sigf(gi), fg = sigf(gf), gv = tanh_fast(gg), og = sigf(go);
            c1 = fmaf(fg, c1, ig * gv);
            hs0[tid] = og * tanh_fast(c1);
        }
        __syncthreads();
    }
}

extern "C" void kernel_launch(void* const* d_in, const int* in_sizes, int n_in,
                              void* d_out, int out_size, void* d_ws, size_t ws_size,
                              hipStream_t stream)
{
    const float* x     = (const float*)d_in[0];
    const float* W_ih1 = (const float*)d_in[1];
    const float* W_hh1 = (const float*)d_in[2];
    const float* b_ih1 = (const float*)d_in[3];
    const float* b_hh1 = (const float*)d_in[4];
    const float* W_ih2 = (const float*)d_in[5];
    const float* W_hh2 = (const float*)d_in[6];
    const float* b_ih2 = (const float*)d_in[7];
    const float* b_hh2 = (const float*)d_in[8];
    const float* W_lin = (const float*)d_in[9];
    const float* b_lin = (const float*)d_in[10];
    float* out = (float*)d_out;

    const size_t smem_bytes = SM_FLOATS * sizeof(float);   // ~127.7 KB < 128 KiB
    static bool attr_set = false;  // idempotent runtime attr (not a stream op)
    if (!attr_set) {
        (void)hipFuncSetAttribute((const void*)lstm_pred_kernel,
                                  hipFuncAttributeMaxDynamicSharedMemorySize,
                                  (int)smem_bytes);
        attr_set = true;
    }

    lstm_pred_kernel<<<B_, 768, smem_bytes, stream>>>(x, W_ih1, W_hh1, b_ih1, b_hh1,
                                                      W_ih2, W_hh2, b_ih2, b_hh2,
                                                      W_lin, b_lin, out);
}

// Round 7
// 1206.779 us; speedup vs baseline: 1.2922x; 1.2922x over previous
//
#include <hip/hip_runtime.h>

// LSTMPredictor: 2-layer LSTMCell (H=51), L=1000 steps + 100 autoregressive,
// B=256 chains. One block/batch element (grid=256=#CUs), 768 threads, 3 groups:
//   G0 (tid   0..203): row j of W_hh1 -> gates1 partial (for h1(t+1))
//   G1 (tid 256..459): row j of W_ih2 -> gatesA(t)
//   G2 (tid 512..715): row j of W_hh2 -> gatesB(t)
//
// R7 KEY FIX: __launch_bounds__ second arg behaves as MIN BLOCKS PER CU
// (CUDA semantics). R3-R6's "(768,3)" demanded 36 waves/CU -> 512/9 = 56 VGPR
// cap -> the allocator was FORCED to spill the 51 weight regs every round
// (observed VGPR_Count 52-56 = exact match; R2's (512,2)->128 cap, obs 112;
// R1's (256,1)->uncapped, obs 136). Grid=256=#CUs means only 1 block/CU ever
// runs, so the old 2nd arg bought nothing. (768,1) -> cap 512/3 = 170 VGPRs,
// demand ~110 -> weights genuinely register-resident at last.
// Structure otherwise identical to R5: 2 barriers/step hot loop, 3 barriers
// for the 101 autoregressive steps; weights pinned via volatile asm "+v".

#define B_   256
#define L_   1000
#define H_   51
#define HP   52
#define G4   204
#define GP   208
#define T_   1100

__device__ __forceinline__ float frcp(float v) { return __builtin_amdgcn_rcpf(v); }
__device__ __forceinline__ float sigf(float v) {
    return frcp(1.0f + __expf(-v));
}
__device__ __forceinline__ float tanh_fast(float v) {
    float a = fminf(fmaxf(v, -9.0f), 9.0f);
    float e = __expf(2.0f * a);
    return (e - 1.0f) * frcp(e + 1.0f);
}

// dot of one float4 h-chunk with 4 named weight scalars
#define DOT4(hv, p0, p1, p2, p3) do { \
    a0 = fmaf(p0, (hv).x, a0); a1 = fmaf(p1, (hv).y, a1); \
    a2 = fmaf(p2, (hv).z, a2); a3 = fmaf(p3, (hv).w, a3); } while (0)

#define MATVEC() do { \
    const float4* h4 = (const float4*)hs[s]; \
    float4 hv0 = h4[0], hv1 = h4[1], hv2 = h4[2], hv3 = h4[3]; \
    float4 hv4 = h4[4], hv5 = h4[5], hv6 = h4[6], hv7 = h4[7]; \
    float4 hv8 = h4[8], hv9 = h4[9], hv10 = h4[10], hv11 = h4[11], hv12 = h4[12]; \
    float a0 = bias, a1 = 0.f, a2 = 0.f, a3 = 0.f; \
    DOT4(hv0,  wr0,  wr1,  wr2,  wr3);  DOT4(hv1,  wr4,  wr5,  wr6,  wr7); \
    DOT4(hv2,  wr8,  wr9,  wr10, wr11); DOT4(hv3,  wr12, wr13, wr14, wr15); \
    DOT4(hv4,  wr16, wr17, wr18, wr19); DOT4(hv5,  wr20, wr21, wr22, wr23); \
    DOT4(hv6,  wr24, wr25, wr26, wr27); DOT4(hv7,  wr28, wr29, wr30, wr31); \
    DOT4(hv8,  wr32, wr33, wr34, wr35); DOT4(hv9,  wr36, wr37, wr38, wr39); \
    DOT4(hv10, wr40, wr41, wr42, wr43); DOT4(hv11, wr44, wr45, wr46, wr47); \
    a0 = fmaf(wr48, hv12.x, a0); a1 = fmaf(wr49, hv12.y, a1); a2 = fmaf(wr50, hv12.z, a2); \
    gdst[0] = (a0 + a1) + (a2 + a3); } while (0)

__global__ __launch_bounds__(768, 1)
void lstm_pred_kernel(const float* __restrict__ x,
                      const float* __restrict__ W_ih1, const float* __restrict__ W_hh1,
                      const float* __restrict__ b_ih1, const float* __restrict__ b_hh1,
                      const float* __restrict__ W_ih2, const float* __restrict__ W_hh2,
                      const float* __restrict__ b_ih2, const float* __restrict__ b_hh2,
                      const float* __restrict__ W_lin, const float* __restrict__ b_lin,
                      float* __restrict__ out)
{
    __shared__ float xrow[L_];
    __shared__ alignas(16) float gall[3 * GP];  // g1partial | gatesA | gatesB
    __shared__ alignas(16) float hs[2][HP];     // hs[0]=h1, hs[1]=h2
    __shared__ float out_s;

    const int tid = threadIdx.x;
    const int b   = blockIdx.x;
    const int g   = tid >> 8;
    const int j   = tid & 255;
    const bool act = (j < G4);
    const int  s   = (g == 2) ? 1 : 0;

    for (int i = tid; i < L_; i += 768) xrow[i] = x[(size_t)b * L_ + i];
    if (tid < HP) { hs[0][tid] = 0.0f; hs[1][tid] = 0.0f; }

    // ---- one weight row per thread: 51 NAMED scalars ----
    const float* wrow = (g == 0) ? (W_hh1 + j * H_)
                      : (g == 1) ? (W_ih2 + j * H_)
                                 : (W_hh2 + j * H_);
    float bias = 0.0f;
    float wr0=0.f,wr1=0.f,wr2=0.f,wr3=0.f,wr4=0.f,wr5=0.f,wr6=0.f,wr7=0.f,
          wr8=0.f,wr9=0.f,wr10=0.f,wr11=0.f,wr12=0.f,wr13=0.f,wr14=0.f,wr15=0.f,
          wr16=0.f,wr17=0.f,wr18=0.f,wr19=0.f,wr20=0.f,wr21=0.f,wr22=0.f,wr23=0.f,
          wr24=0.f,wr25=0.f,wr26=0.f,wr27=0.f,wr28=0.f,wr29=0.f,wr30=0.f,wr31=0.f,
          wr32=0.f,wr33=0.f,wr34=0.f,wr35=0.f,wr36=0.f,wr37=0.f,wr38=0.f,wr39=0.f,
          wr40=0.f,wr41=0.f,wr42=0.f,wr43=0.f,wr44=0.f,wr45=0.f,wr46=0.f,wr47=0.f,
          wr48=0.f,wr49=0.f,wr50=0.f;
    if (act) {
        if (g == 0)      bias = b_ih1[j] + b_hh1[j];
        else if (g == 1) bias = b_ih2[j] + b_hh2[j];
        wr0 =wrow[0];  wr1 =wrow[1];  wr2 =wrow[2];  wr3 =wrow[3];
        wr4 =wrow[4];  wr5 =wrow[5];  wr6 =wrow[6];  wr7 =wrow[7];
        wr8 =wrow[8];  wr9 =wrow[9];  wr10=wrow[10]; wr11=wrow[11];
        wr12=wrow[12]; wr13=wrow[13]; wr14=wrow[14]; wr15=wrow[15];
        wr16=wrow[16]; wr17=wrow[17]; wr18=wrow[18]; wr19=wrow[19];
        wr20=wrow[20]; wr21=wrow[21]; wr22=wrow[22]; wr23=wrow[23];
        wr24=wrow[24]; wr25=wrow[25]; wr26=wrow[26]; wr27=wrow[27];
        wr28=wrow[28]; wr29=wrow[29]; wr30=wrow[30]; wr31=wrow[31];
        wr32=wrow[32]; wr33=wrow[33]; wr34=wrow[34]; wr35=wrow[35];
        wr36=wrow[36]; wr37=wrow[37]; wr38=wrow[38]; wr39=wrow[39];
        wr40=wrow[40]; wr41=wrow[41]; wr42=wrow[42]; wr43=wrow[43];
        wr44=wrow[44]; wr45=wrow[45]; wr46=wrow[46]; wr47=wrow[47];
        wr48=wrow[48]; wr49=wrow[49]; wr50=wrow[50];
    }
    // PIN: values opaque -> no remat; with the 170-VGPR budget they now FIT.
    asm volatile("" :
        "+v"(wr0),"+v"(wr1),"+v"(wr2),"+v"(wr3),"+v"(wr4),"+v"(wr5),"+v"(wr6),
        "+v"(wr7),"+v"(wr8),"+v"(wr9),"+v"(wr10),"+v"(wr11),"+v"(wr12),"+v"(wr13),
        "+v"(wr14),"+v"(wr15),"+v"(wr16),"+v"(wr17),"+v"(wr18),"+v"(wr19),
        "+v"(wr20),"+v"(wr21),"+v"(wr22),"+v"(wr23),"+v"(wr24),"+v"(wr25));
    asm volatile("" :
        "+v"(wr26),"+v"(wr27),"+v"(wr28),"+v"(wr29),"+v"(wr30),"+v"(wr31),
        "+v"(wr32),"+v"(wr33),"+v"(wr34),"+v"(wr35),"+v"(wr36),"+v"(wr37),
        "+v"(wr38),"+v"(wr39),"+v"(wr40),"+v"(wr41),"+v"(wr42),"+v"(wr43),
        "+v"(wr44),"+v"(wr45),"+v"(wr46),"+v"(wr47),"+v"(wr48),"+v"(wr49),
        "+v"(wr50),"+v"(bias));
    float* gdst = gall + g * GP + j;

    // update-lane extras
    float wi0 = 0.f, wi1 = 0.f, wi2 = 0.f, wi3 = 0.f, wlin = 0.f;
    if (tid < H_) {
        wi0 = W_ih1[tid];
        wi1 = W_ih1[tid + H_];
        wi2 = W_ih1[tid + 2 * H_];
        wi3 = W_ih1[tid + 3 * H_];
    }
    if (tid >= 256 && tid < 256 + H_) wlin = W_lin[tid - 256];
    const float blin = b_lin[0];

    float c1 = 0.f, c2 = 0.f;
    float* outp = out + (size_t)b * T_;

    // ---- prologue: h1(0) (h1(-1)=0 -> gates1 partial = bias1) ----
    if (g == 0 && act) gall[j] = bias;
    __syncthreads();
    if (tid < H_) {
        const float xv = xrow[0];
        float gi = fmaf(wi0, xv, gall[tid]);
        float gf = fmaf(wi1, xv, gall[tid + H_]);
        float gg = fmaf(wi2, xv, gall[tid + 2 * H_]);
        float go = fmaf(wi3, xv, gall[tid + 3 * H_]);
        float ig = sigf(gi), fg = sigf(gf), gv = tanh_fast(gg), og = sigf(go);
        c1 = fmaf(fg, c1, ig * gv);
        hs[0][tid] = og * tanh_fast(c1);
    }
    __syncthreads();

    // ========== hot loop: t = 0..998, 2 barriers/step ==========
    for (int t = 0; t < L_ - 1; ++t) {
        if (act) MATVEC();
        __syncthreads();

        // Phase B1 (wave 4): h2(t) update + output
        if (tid >= 256 && tid < 320) {
            float p = 0.f;
            const int q2 = tid - 256;
            if (q2 < H_) {
                float gi = gall[GP + q2]        + gall[2*GP + q2];
                float gf = gall[GP + q2 +   H_] + gall[2*GP + q2 +   H_];
                float gg = gall[GP + q2 + 2*H_] + gall[2*GP + q2 + 2*H_];
                float go = gall[GP + q2 + 3*H_] + gall[2*GP + q2 + 3*H_];
                float ig = sigf(gi), fg = sigf(gf), gv = tanh_fast(gg), og = sigf(go);
                c2 = fmaf(fg, c2, ig * gv);
                float h2n = og * tanh_fast(c2);
                hs[1][q2] = h2n;
                p = h2n * wlin;
            }
#pragma unroll
            for (int off = 32; off > 0; off >>= 1) p += __shfl_down(p, off);
            if (q2 == 0) outp[t] = p + blin;
        }
        // Phase B2 (wave 0, concurrent): h1(t+1)
        if (tid < H_) {
            const float xv = xrow[t + 1];
            float gi = fmaf(wi0, xv, gall[tid]);
            float gf = fmaf(wi1, xv, gall[tid + H_]);
            float gg = fmaf(wi2, xv, gall[tid + 2 * H_]);
            float go = fmaf(wi3, xv, gall[tid + 3 * H_]);
            float ig = sigf(gi), fg = sigf(gf), gv = tanh_fast(gg), og = sigf(go);
            c1 = fmaf(fg, c1, ig * gv);
            hs[0][tid] = og * tanh_fast(c1);
        }
        __syncthreads();
    }

    // ========== future loop: t = 999..1099 (x <- out_s), 3 barriers ==========
    for (int t = L_ - 1; t < T_; ++t) {
        if (act) MATVEC();
        __syncthreads();

        if (tid >= 256 && tid < 320) {
            float p = 0.f;
            const int q2 = tid - 256;
            if (q2 < H_) {
                float gi = gall[GP + q2]        + gall[2*GP + q2];
                float gf = gall[GP + q2 +   H_] + gall[2*GP + q2 +   H_];
                float gg = gall[GP + q2 + 2*H_] + gall[2*GP + q2 + 2*H_];
                float go = gall[GP + q2 + 3*H_] + gall[2*GP + q2 + 3*H_];
                float ig = sigf(gi), fg = sigf(gf), gv = tanh_fast(gg), og = sigf(go);
                c2 = fmaf(fg, c2, ig * gv);
                float h2n = og * tanh_fast(c2);
                hs[1][q2] = h2n;
                p = h2n * wlin;
            }
#pragma unroll
            for (int off = 32; off > 0; off >>= 1) p += __shfl_down(p, off);
            if (q2 == 0) { float o = p + blin; out_s = o; outp[t] = o; }
        }
        __syncthreads();   // out_s visible to wave 0

        if (tid < H_) {
            const float xv = out_s;
            float gi = fmaf(wi0, xv, gall[tid]);
            float gf = fmaf(wi1, xv, gall[tid + H_]);
            float gg = fmaf(wi2, xv, gall[tid + 2 * H_]);
            float go = fmaf(wi3, xv, gall[tid + 3 * H_]);
            float ig = sigf(gi), fg = sigf(gf), gv = tanh_fast(gg), og = sigf(go);
            c1 = fmaf(fg, c1, ig * gv);
            hs[0][tid] = og * tanh_fast(c1);
        }
        __syncthreads();
    }
}

extern "C" void kernel_launch(void* const* d_in, const int* in_sizes, int n_in,
                              void* d_out, int out_size, void* d_ws, size_t ws_size,
                              hipStream_t stream)
{
    const float* x     = (const float*)d_in[0];
    const float* W_ih1 = (const float*)d_in[1];
    const float* W_hh1 = (const float*)d_in[2];
    const float* b_ih1 = (const float*)d_in[3];
    const float* b_hh1 = (const float*)d_in[4];
    const float* W_ih2 = (const float*)d_in[5];
    const float* W_hh2 = (const float*)d_in[6];
    const float* b_ih2 = (const float*)d_in[7];
    const float* b_hh2 = (const float*)d_in[8];
    const float* W_lin = (const float*)d_in[9];
    const float* b_lin = (const float*)d_in[10];
    float* out = (float*)d_out;

    lstm_pred_kernel<<<B_, 768, 0, stream>>>(x, W_ih1, W_hh1, b_ih1, b_hh1,
                                             W_ih2, W_hh2, b_ih2, b_hh2,
                                             W_lin, b_lin, out);
}